// Round 1
// baseline (678.695 us; speedup 1.0000x reference)
//
#include <hip/hip_runtime.h>

#define N_NODES 100000
#define N_EDGES 3200000

constexpr float DSIGMA_DT  = -0.0001f;
constexpr float PHI_THRESH = 0.3f;
constexpr float EPS        = 1e-8f;

// Extract T = x[:,3] into a compact array for cache-dense gathers.
__global__ void extract_T_kernel(const float* __restrict__ x,
                                 float* __restrict__ Tc) {
    int i = blockIdx.x * blockDim.x + threadIdx.x;
    if (i < N_NODES) Tc[i] = x[i * 9 + 3];
}

// One thread per edge: gather endpoints, compute contribution, scatter-add.
__global__ void edge_scatter_kernel(const int* __restrict__ ei,
                                    const float* __restrict__ Tc,
                                    const float* __restrict__ pos,
                                    float* __restrict__ accum,   // d_out used as num accumulator
                                    unsigned int* __restrict__ cnt) {
    int e = blockIdx.x * blockDim.x + threadIdx.x;
    if (e >= N_EDGES) return;
    int s = ei[e];
    int d = ei[N_EDGES + e];

    float dT = Tc[s] - Tc[d];
    float px = pos[3 * s]     - pos[3 * d];
    float py = pos[3 * s + 1] - pos[3 * d + 1];
    float pz = pos[3 * s + 2] - pos[3 * d + 2];
    float dist2 = px * px + py * py + pz * pz + EPS;
    float w = dT / dist2;

    atomicAdd(&accum[3 * d],     w * px);
    atomicAdd(&accum[3 * d + 1], w * py);
    atomicAdd(&accum[3 * d + 2], w * pz);
    atomicAdd(&cnt[d], 1u);
}

// One thread per node: out = mask * DSIGMA_DT * num / max(cnt,1)
__global__ void finalize_kernel(const float* __restrict__ x,
                                const unsigned int* __restrict__ cnt,
                                float* __restrict__ out) {
    int i = blockIdx.x * blockDim.x + threadIdx.x;
    if (i >= N_NODES) return;
    float phi = x[i * 9 + 8];
    float c = (float)(cnt[i] > 1u ? cnt[i] : 1u);
    float m = (fabsf(phi) < PHI_THRESH) ? (DSIGMA_DT / c) : 0.0f;
    out[3 * i]     *= m;
    out[3 * i + 1] *= m;
    out[3 * i + 2] *= m;
}

extern "C" void kernel_launch(void* const* d_in, const int* in_sizes, int n_in,
                              void* d_out, int out_size, void* d_ws, size_t ws_size,
                              hipStream_t stream) {
    const float* x   = (const float*)d_in[0];
    const float* pos = (const float*)d_in[1];
    const int*   ei  = (const int*)d_in[2];
    float* out = (float*)d_out;

    // ws layout: [Tc: N_NODES floats][cnt: N_NODES uints]
    float* Tc = (float*)d_ws;
    unsigned int* cnt = (unsigned int*)((char*)d_ws + (size_t)N_NODES * sizeof(float));

    // Zero accumulators (d_out and d_ws are poisoned 0xAA before every launch).
    hipMemsetAsync(d_out, 0, (size_t)N_NODES * 3 * sizeof(float), stream);
    hipMemsetAsync(cnt, 0, (size_t)N_NODES * sizeof(unsigned int), stream);

    const int B = 256;
    extract_T_kernel<<<(N_NODES + B - 1) / B, B, 0, stream>>>(x, Tc);
    edge_scatter_kernel<<<(N_EDGES + B - 1) / B, B, 0, stream>>>(ei, Tc, pos, out, cnt);
    finalize_kernel<<<(N_NODES + B - 1) / B, B, 0, stream>>>(x, cnt, out);
}